// Round 3
// baseline (355.924 us; speedup 1.0000x reference)
//
#include <hip/hip_runtime.h>
#include <math.h>

// LBP radius=1, n_points=8 on NCHW (16,64,224,224) f32.
// Round-3 structure: each thread computes the SAME 8-tall x 4-wide tile in
// TWO adjacent planes (2q, 2q+1). Address math is shared; all 60 window
// loads issue as one batch (2x memory-level parallelism per latency stall);
// compute per stall doubles. Round-2 showed one 8x4 tile/wave leaves ~50%
// of cycles stalled even with branch-free batched loads.
// Mask build uses v_cmp + v_addc_co_u32 (2 VALU/bit, m = 2m + cmp) instead
// of cmp+cndmask+or (3 VALU/bit): ~15% off the VALU floor, same compares.
// p=0,2,4,6 exact neighbor compares; p=1,3,5,7 bilinear diagonals (bit-exact
// vs numpy f32: per-term rounding, left-to-right sum, no FMA contraction).
#define HH 224
#define WW 224
#define PLANES (16 * 64)
#define QPLANES (PLANES / 2)                  // 512 plane-pairs
#define TILE_H 8
#define TILES_X (WW / 4)                      // 56
#define TILES_Y (HH / TILE_H)                 // 28
#define TILES_PER_PLANE (TILES_X * TILES_Y)   // 1568
#define TOTAL_THREADS (QPLANES * TILES_PER_PLANE)  // 802,816

struct LbpWeights {
    float w1[4];
    float w3[4];
    float w5[4];
    float w7[4];
};

__global__ __launch_bounds__(256, 3) void lbp_kernel(const float* __restrict__ x,
                                                     float* __restrict__ out,
                                                     LbpWeights wt) {
    int tid = blockIdx.x * 256 + threadIdx.x;

    int q = tid / TILES_PER_PLANE;
    int t = tid - q * TILES_PER_PLANE;
    int tr = t / TILES_X;
    int tc = t - tr * TILES_X;
    int r0 = tr * TILE_H, c0 = tc * 4;

    const float* pb0 = x + (size_t)(2 * q) * (HH * WW);

    bool cm = (c0 > 0), cp = (c0 + 4 < WW);
    // Safe (clamped) column offsets relative to rp; value is zero-selected
    // when out of image, so the clamped address only has to be in-bounds.
    int cl_off = cm ? -1 : 0;
    int cr_off = cp ? 4 : 3;

    // aP[i][k]: window rows r0-1..r0+TILE_H (i=0..TILE_H+1), cols c0-1..c0+4
    // (k=0..5), zero outside the image (matches constant-0 padding).
    float a0[TILE_H + 2][6];
    float a1[TILE_H + 2][6];
#pragma unroll
    for (int i = 0; i < TILE_H + 2; i++) {
        int rr = r0 - 1 + i;
        int rrc = rr < 0 ? 0 : (rr > HH - 1 ? HH - 1 : rr);
        bool rok = (rr >= 0) && (rr < HH);
        const float* rp0 = pb0 + rrc * WW + c0;
        const float* rp1 = rp0 + HH * WW;  // next plane, same offset
        float4 v0 = *(const float4*)rp0;
        float l0 = rp0[cl_off];
        float r0v = rp0[cr_off];
        float4 v1 = *(const float4*)rp1;
        float l1 = rp1[cl_off];
        float r1v = rp1[cr_off];
        a0[i][1] = rok ? v0.x : 0.0f;
        a0[i][2] = rok ? v0.y : 0.0f;
        a0[i][3] = rok ? v0.z : 0.0f;
        a0[i][4] = rok ? v0.w : 0.0f;
        a0[i][0] = (rok && cm) ? l0 : 0.0f;
        a0[i][5] = (rok && cp) ? r0v : 0.0f;
        a1[i][1] = rok ? v1.x : 0.0f;
        a1[i][2] = rok ? v1.y : 0.0f;
        a1[i][3] = rok ? v1.z : 0.0f;
        a1[i][4] = rok ? v1.w : 0.0f;
        a1[i][0] = (rok && cm) ? l1 : 0.0f;
        a1[i][5] = (rok && cp) ? r1v : 0.0f;
    }

    float* ob0 = out + (size_t)(2 * q) * (HH * WW) + r0 * WW + c0;

    auto compute = [&](const float (&a)[TILE_H + 2][6], float* ob) {
#pragma unroll
        for (int j = 0; j < TILE_H; j++) {
            float res[4];
#pragma unroll
            for (int k = 0; k < 4; k++) {
                float ctr = a[j + 1][k + 1];
                float n00 = a[j][k],     n01 = a[j][k + 1],     n02 = a[j][k + 2];
                float n10 = a[j + 1][k],                        n12 = a[j + 1][k + 2];
                float n20 = a[j + 2][k], n21 = a[j + 2][k + 1], n22 = a[j + 2][k + 2];

                float v1, v3, v5, v7;
                {
#pragma clang fp contract(off)
                    // p=1: r0=-1,c0=0 -> (n01, n02, ctr, n12)
                    v1 = ((wt.w1[0] * n01 + wt.w1[1] * n02) + wt.w1[2] * ctr) + wt.w1[3] * n12;
                    // p=3: r0=-1,c0=-1 -> (n00, n01, n10, ctr)
                    v3 = ((wt.w3[0] * n00 + wt.w3[1] * n01) + wt.w3[2] * n10) + wt.w3[3] * ctr;
                    // p=5: r0=0,c0=-1 -> (n10, ctr, n20, n21)
                    v5 = ((wt.w5[0] * n10 + wt.w5[1] * ctr) + wt.w5[2] * n20) + wt.w5[3] * n21;
                    // p=7: r0=0,c0=0 -> (ctr, n12, n21, n22)
                    v7 = ((wt.w7[0] * ctr + wt.w7[1] * n12) + wt.w7[2] * n21) + wt.w7[3] * n22;
                }

                // m = sum 2^p * (v_p >= ctr), accumulated MSB-first:
                // m = 2*m + bit via v_cmp (vcc) + v_addc_co_u32 (carry-in).
                unsigned m = 0u;
#define LBP_BIT(val)                                                   \
    asm("v_cmp_ge_f32 vcc, %1, %2\n\t"                                 \
        "v_addc_co_u32 %0, vcc, %0, %0, vcc"                           \
        : "+v"(m) : "v"(val), "v"(ctr) : "vcc")
                LBP_BIT(v7);   // p=7
                LBP_BIT(n21);  // p=6
                LBP_BIT(v5);   // p=5
                LBP_BIT(n10);  // p=4
                LBP_BIT(v3);   // p=3
                LBP_BIT(n01);  // p=2
                LBP_BIT(v1);   // p=1
                LBP_BIT(n12);  // p=0
#undef LBP_BIT
                res[k] = (float)m;
            }
            *(float4*)(ob + j * WW) = make_float4(res[0], res[1], res[2], res[3]);
        }
    };

    compute(a0, ob0);
    compute(a1, ob0 + HH * WW);
}

extern "C" void kernel_launch(void* const* d_in, const int* in_sizes, int n_in,
                              void* d_out, int out_size, void* d_ws, size_t ws_size,
                              hipStream_t stream) {
    (void)in_sizes; (void)n_in; (void)d_ws; (void)ws_size; (void)out_size;
    const float* x = (const float*)d_in[0];
    float* out = (float*)d_out;

    // Replicate np.round(-R*sin(ang), 8) = rint(v*1e8)/1e8 in double; weights
    // are float64 products rounded to f32 (NEP-50 weak-scalar semantics).
    LbpWeights wt;
    float* slots[4] = {wt.w1, wt.w3, wt.w5, wt.w7};
    const int diag_p[4] = {1, 3, 5, 7};
    for (int i = 0; i < 4; i++) {
        int p = diag_p[i];
        double ang = (2.0 * M_PI * (double)p) / 8.0;
        double dr = rint(-sin(ang) * 1e8) / 1e8;
        double dc = rint( cos(ang) * 1e8) / 1e8;
        double r0 = floor(dr), c0 = floor(dc);
        double fr = dr - r0, fc = dc - c0;
        slots[i][0] = (float)((1.0 - fr) * (1.0 - fc));
        slots[i][1] = (float)((1.0 - fr) * fc);
        slots[i][2] = (float)(fr * (1.0 - fc));
        slots[i][3] = (float)(fr * fc);
    }

    const int block = 256;
    const int grid = TOTAL_THREADS / block;  // 3136, exact
    lbp_kernel<<<grid, block, 0, stream>>>(x, out, wt);
}

// Round 4
// 350.922 us; speedup vs baseline: 1.0143x; 1.0143x over previous
//
#include <hip/hip_runtime.h>
#include <math.h>

// LBP radius=1, n_points=8 on NCHW (16,64,224,224) f32.
// Round-4 structure: rolling-window strip kernel. Each thread owns a
// 4-wide x 16-tall strip. A 3-row (x6 cols) register window rolls down the
// strip; each phase prefetches row r+2 (issued one full compute-phase before
// use), finalizes row r+1 (zero-select for out-of-image), computes output
// row r, stores one float4. Four named phases in a ROLLED loop give free
// period-4 buffer rotation with all-static indexing (no scratch).
// Why: rounds 0-3 showed the batch structure (big window load -> one wait ->
// compute) is pinned at ~120us regardless of batch size: all ~3.3 resident
// waves/SIMD stall together, and growing the batch grows VGPR which caps the
// occupancy that would hide the stall. The rolling window needs only ~36 row
// floats -> ~60-80 VGPR -> 6-8 waves/SIMD, AND pre-covers each row's load
// latency under the previous row's compute, AND keeps the loop body ~5KB
// (I$-resident) instead of ~20KB straight-line.
// p=0,2,4,6 exact neighbor compares; p=1,3,5,7 bilinear diagonals (bit-exact
// vs numpy f32: per-term rounding, left-to-right sum, no FMA contraction).
// Mask build: v_cmp + v_addc_co_u32 (2 VALU/bit), verified bit-exact in R3.
#define HH 224
#define WW 224
#define PLANES (16 * 64)
#define STRIP_H 16
#define TILES_X (WW / 4)                       // 56
#define STRIPS_Y (HH / STRIP_H)                // 14
#define STRIPS_PER_PLANE (TILES_X * STRIPS_Y)  // 784
#define TOTAL_THREADS (PLANES * STRIPS_PER_PLANE)  // 802,816

struct LbpWeights {
    float w1[4];
    float w3[4];
    float w5[4];
    float w7[4];
};

struct RawRow { float4 q; float l, r; };   // as-loaded, pre-select
struct Row    { float v[6]; };             // finalized (zeros outside image)

__global__ __launch_bounds__(256, 6) void lbp_kernel(const float* __restrict__ x,
                                                     float* __restrict__ out,
                                                     LbpWeights wt) {
    int tid = blockIdx.x * 256 + threadIdx.x;

    int plane = tid / STRIPS_PER_PLANE;
    int t = tid - plane * STRIPS_PER_PLANE;
    int tr = t / TILES_X;
    int tc = t - tr * TILES_X;
    int r0 = tr * STRIP_H, c0 = tc * 4;

    const float* pb = x + (size_t)plane * (HH * WW);

    bool cm = (c0 > 0), cp = (c0 + 4 < WW);
    // Clamped-safe column offsets; out-of-image values are zero-selected, so
    // the address only has to be in-bounds.
    int cl_off = cm ? -1 : 0;
    int cr_off = cp ? 4 : 3;

    // Issue the 3 loads for image row rr (clamped address; no selects yet, so
    // the loads stay in flight until finalize one phase later).
    auto issue = [&](RawRow& s, int rr) {
        int rrc = rr < 0 ? 0 : (rr > HH - 1 ? HH - 1 : rr);
        const float* rp = pb + rrc * WW + c0;
        s.q = *(const float4*)rp;
        s.l = rp[cl_off];
        s.r = rp[cr_off];
    };
    // Apply zero-selects (constant-0 padding semantics).
    auto finalize = [&](Row& f, const RawRow& s, int rr) {
        bool ok = (unsigned)rr < (unsigned)HH;
        f.v[1] = ok ? s.q.x : 0.0f;
        f.v[2] = ok ? s.q.y : 0.0f;
        f.v[3] = ok ? s.q.z : 0.0f;
        f.v[4] = ok ? s.q.w : 0.0f;
        f.v[0] = (ok && cm) ? s.l : 0.0f;
        f.v[5] = (ok && cp) ? s.r : 0.0f;
    };
    // Compute one output row (4 px) from rows A (above), B (center), C (below).
    auto compute_row = [&](const Row& A, const Row& B, const Row& C, float* orow) {
        float res[4];
#pragma unroll
        for (int k = 0; k < 4; k++) {
            float ctr = B.v[k + 1];
            float n00 = A.v[k], n01 = A.v[k + 1], n02 = A.v[k + 2];
            float n10 = B.v[k],                   n12 = B.v[k + 2];
            float n20 = C.v[k], n21 = C.v[k + 1], n22 = C.v[k + 2];

            float v1, v3, v5, v7;
            {
#pragma clang fp contract(off)
                // p=1: r0=-1,c0=0 -> (n01, n02, ctr, n12)
                v1 = ((wt.w1[0] * n01 + wt.w1[1] * n02) + wt.w1[2] * ctr) + wt.w1[3] * n12;
                // p=3: r0=-1,c0=-1 -> (n00, n01, n10, ctr)
                v3 = ((wt.w3[0] * n00 + wt.w3[1] * n01) + wt.w3[2] * n10) + wt.w3[3] * ctr;
                // p=5: r0=0,c0=-1 -> (n10, ctr, n20, n21)
                v5 = ((wt.w5[0] * n10 + wt.w5[1] * ctr) + wt.w5[2] * n20) + wt.w5[3] * n21;
                // p=7: r0=0,c0=0 -> (ctr, n12, n21, n22)
                v7 = ((wt.w7[0] * ctr + wt.w7[1] * n12) + wt.w7[2] * n21) + wt.w7[3] * n22;
            }

            // m = sum 2^p * (v_p >= ctr), MSB-first: m = 2m + cmp.
            unsigned m = 0u;
#define LBP_BIT(val)                                                   \
    asm("v_cmp_ge_f32 vcc, %1, %2\n\t"                                 \
        "v_addc_co_u32 %0, vcc, %0, %0, vcc"                           \
        : "+v"(m) : "v"(val), "v"(ctr) : "vcc")
            LBP_BIT(v7);   // p=7
            LBP_BIT(n21);  // p=6
            LBP_BIT(v5);   // p=5
            LBP_BIT(n10);  // p=4
            LBP_BIT(v3);   // p=3
            LBP_BIT(n01);  // p=2
            LBP_BIT(v1);   // p=1
            LBP_BIT(n12);  // p=0
#undef LBP_BIT
            res[k] = (float)m;
        }
        *(float4*)orow = make_float4(res[0], res[1], res[2], res[3]);
    };

    // Row slot for image row (r0+g) is F[(g+1)%4].
    Row F0, F1, F2, F3;
    RawRow Ra, Rb;

    // Prologue: finalize rows r0-1, r0, r0+1; issue raw row r0+2.
    {
        RawRow p0; issue(p0, r0 - 1); finalize(F0, p0, r0 - 1);
        RawRow p1; issue(p1, r0);     finalize(F1, p1, r0);
        RawRow p2; issue(p2, r0 + 1); finalize(F2, p2, r0 + 1);
    }
    issue(Ra, r0 + 2);

    float* ob = out + (size_t)plane * (HH * WW) + r0 * WW + c0;

#pragma unroll 1
    for (int rb = 0; rb < STRIP_H / 4; rb++) {
        int g = rb * 4;
        // phase 0: compute row g   (slots F0,F1,F2); finalize row g+2 -> F3
        issue(Rb, r0 + g + 3);
        finalize(F3, Ra, r0 + g + 2);
        compute_row(F0, F1, F2, ob + (g + 0) * WW);
        // phase 1: compute row g+1 (slots F1,F2,F3); finalize row g+3 -> F0
        issue(Ra, r0 + g + 4);
        finalize(F0, Rb, r0 + g + 3);
        compute_row(F1, F2, F3, ob + (g + 1) * WW);
        // phase 2: compute row g+2 (slots F2,F3,F0); finalize row g+4 -> F1
        issue(Rb, r0 + g + 5);
        finalize(F1, Ra, r0 + g + 4);
        compute_row(F2, F3, F0, ob + (g + 2) * WW);
        // phase 3: compute row g+3 (slots F3,F0,F1); finalize row g+5 -> F2
        issue(Ra, r0 + g + 6);
        finalize(F2, Rb, r0 + g + 5);
        compute_row(F3, F0, F1, ob + (g + 3) * WW);
    }
}

extern "C" void kernel_launch(void* const* d_in, const int* in_sizes, int n_in,
                              void* d_out, int out_size, void* d_ws, size_t ws_size,
                              hipStream_t stream) {
    (void)in_sizes; (void)n_in; (void)d_ws; (void)ws_size; (void)out_size;
    const float* x = (const float*)d_in[0];
    float* out = (float*)d_out;

    // Replicate np.round(-R*sin(ang), 8) = rint(v*1e8)/1e8 in double; weights
    // are float64 products rounded to f32 (NEP-50 weak-scalar semantics).
    LbpWeights wt;
    float* slots[4] = {wt.w1, wt.w3, wt.w5, wt.w7};
    const int diag_p[4] = {1, 3, 5, 7};
    for (int i = 0; i < 4; i++) {
        int p = diag_p[i];
        double ang = (2.0 * M_PI * (double)p) / 8.0;
        double dr = rint(-sin(ang) * 1e8) / 1e8;
        double dc = rint( cos(ang) * 1e8) / 1e8;
        double r0 = floor(dr), c0 = floor(dc);
        double fr = dr - r0, fc = dc - c0;
        slots[i][0] = (float)((1.0 - fr) * (1.0 - fc));
        slots[i][1] = (float)((1.0 - fr) * fc);
        slots[i][2] = (float)(fr * (1.0 - fc));
        slots[i][3] = (float)(fr * fc);
    }

    const int block = 256;
    const int grid = TOTAL_THREADS / block;  // 3136, exact
    lbp_kernel<<<grid, block, 0, stream>>>(x, out, wt);
}